// Round 1
// baseline (248.174 us; speedup 1.0000x reference)
//
#include <hip/hip_runtime.h>
#include <stdint.h>

#define E_DIM 1024
#define N_HEADS 16
#define HEAD_D 64
#define BATCH 2
#define SEQ 2048
#define M_ROWS (BATCH*SEQ)   // 4096

typedef __attribute__((ext_vector_type(8))) short short8;
typedef __attribute__((ext_vector_type(4))) float f32x4;
typedef __attribute__((ext_vector_type(4))) int i32x4;

__device__ __forceinline__ unsigned short f2bf(float f) {
  uint32_t u = __float_as_uint(f);
  u += 0x7FFFu + ((u >> 16) & 1u);   // RTNE
  return (unsigned short)(u >> 16);
}

// async global->LDS, 16B per lane; LDS dest = wave-uniform base + lane*16
__device__ __forceinline__ void gload_lds16(const void* g, void* l) {
  __builtin_amdgcn_global_load_lds(
      (const __attribute__((address_space(1))) uint32_t*)(uintptr_t)g,
      (__attribute__((address_space(3))) uint32_t*)(uint32_t)(uintptr_t)l,
      16, 0, 0);
}

__global__ void cvt_f32_bf16(const float* __restrict__ src,
                             unsigned short* __restrict__ dst, int n8) {
  int i = blockIdx.x * blockDim.x + threadIdx.x;
  if (i >= n8) return;
  f32x4 a = ((const f32x4*)src)[2*i];
  f32x4 b = ((const f32x4*)src)[2*i + 1];
  union { unsigned short us[8]; i32x4 v; } o;
  o.us[0] = f2bf(a[0]); o.us[1] = f2bf(a[1]);
  o.us[2] = f2bf(a[2]); o.us[3] = f2bf(a[3]);
  o.us[4] = f2bf(b[0]); o.us[5] = f2bf(b[1]);
  o.us[6] = f2bf(b[2]); o.us[7] = f2bf(b[3]);
  ((i32x4*)dst)[i] = o.v;
}

// C[m][n] = (sum_k A[m][k]*B[n][k] + bias[n]) * scale
// A: [M][K] bf16, B: [N][K] bf16 (nn.Linear weight), 128x64 tile, BK=64.
// LDS swizzle: LDS[row][kc] = G[row][kc ^ (row&7)] (16B chunks), linear dest +
// inverse-swizzled global source (rule #21), swizzled ds_read_b128.
template<int OUT_BF16>
__global__ __launch_bounds__(256, 2)
void gemm_bt(const unsigned short* __restrict__ A,
             const unsigned short* __restrict__ Bm,
             const float* __restrict__ bias,
             void* __restrict__ Cout,
             int M, int N, int K, float scale) {
  constexpr int BM = 128, BN = 64, BK = 64;
  __shared__ __attribute__((aligned(16))) unsigned short Al[BM*BK];
  __shared__ __attribute__((aligned(16))) unsigned short Bl[BN*BK];
  const int tid  = threadIdx.x;
  const int lane = tid & 63, w = tid >> 6;
  const int wm = w >> 1, wn = w & 1;          // wave tile 64x32
  const int l15 = lane & 15, l4 = lane >> 4, l7 = lane & 7;
  const int m0 = blockIdx.y * BM, n0 = blockIdx.x * BN;
  const int jr = lane >> 3, jc = lane & 7;
  const int kcg = jc ^ jr;                    // pre-swizzled global chunk

  f32x4 zero = {0.f, 0.f, 0.f, 0.f};
  f32x4 acc[4][2];
  for (int i = 0; i < 4; ++i) for (int j = 0; j < 2; ++j) acc[i][j] = zero;

  for (int kt = 0; kt < K; kt += BK) {
    __syncthreads();
#pragma unroll
    for (int t = 0; t < 4; ++t) {            // A: 16 issues of 1KB, 4/wave
      int ia = w*4 + t;
      const char* src = (const char*)A +
          ((size_t)(m0 + ia*8 + jr)*K + kt)*2 + (kcg << 4);
      gload_lds16(src, (char*)Al + ia*1024);
    }
#pragma unroll
    for (int t = 0; t < 2; ++t) {            // B: 8 issues, 2/wave
      int ib = w*2 + t;
      const char* src = (const char*)Bm +
          ((size_t)(n0 + ib*8 + jr)*K + kt)*2 + (kcg << 4);
      gload_lds16(src, (char*)Bl + ib*1024);
    }
    __syncthreads();
#pragma unroll
    for (int ks = 0; ks < 2; ++ks) {
      const int sw = ((ks*4 + l4) ^ l7) << 4;
      short8 af[4], bf[2];
#pragma unroll
      for (int mf = 0; mf < 4; ++mf)
        af[mf] = *(const short8*)((const char*)Al + (wm*64 + mf*16 + l15)*128 + sw);
#pragma unroll
      for (int nf = 0; nf < 2; ++nf)
        bf[nf] = *(const short8*)((const char*)Bl + (wn*32 + nf*16 + l15)*128 + sw);
#pragma unroll
      for (int mf = 0; mf < 4; ++mf)
#pragma unroll
        for (int nf = 0; nf < 2; ++nf)
          acc[mf][nf] = __builtin_amdgcn_mfma_f32_16x16x32_bf16(
              af[mf], bf[nf], acc[mf][nf], 0, 0, 0);
    }
  }
  // epilogue: C row = m0+wm*64+mf*16+l4*4+r, col = n0+wn*32+nf*16+l15
#pragma unroll
  for (int nf = 0; nf < 2; ++nf) {
    const int col = n0 + wn*32 + nf*16 + l15;
    const float bv = bias[col];
#pragma unroll
    for (int mf = 0; mf < 4; ++mf) {
      const int rowb = m0 + wm*64 + mf*16 + l4*4;
#pragma unroll
      for (int r = 0; r < 4; ++r) {
        float v = (acc[mf][nf][r] + bv) * scale;
        if (OUT_BF16)
          ((unsigned short*)Cout)[(size_t)(rowb + r)*N + col] = f2bf(v);
        else
          ((float*)Cout)[(size_t)(rowb + r)*N + col] = v;
      }
    }
  }
}

// Flash attention, non-causal. Q pre-scaled by 0.125*log2(e) -> exp2 domain.
// Block: (q-tile 64) x (b*H). 4 waves, 16 q-rows each. KV tiles of 64.
__global__ __launch_bounds__(256, 2)
void attn_fwd(const unsigned short* __restrict__ Q,
              const unsigned short* __restrict__ Kk,
              const unsigned short* __restrict__ V,
              unsigned short* __restrict__ O) {
  __shared__ __attribute__((aligned(16))) unsigned short K_lds[64*64];   // swizzled
  __shared__ __attribute__((aligned(16))) unsigned short Vt_lds[64*64];  // V^T, swizzled
  __shared__ __attribute__((aligned(16))) unsigned short P_lds[4][16*72];// per-wave, padded
  const int tid  = threadIdx.x;
  const int lane = tid & 63, w = tid >> 6;
  const int l15 = lane & 15, l4 = lane >> 4, l7 = lane & 7;
  const int bh = blockIdx.y;
  const int b = bh >> 4, h = bh & 15;
  const int q0 = blockIdx.x * 64;

  // Q fragments held in registers for the whole KV loop
  const size_t rowQ = (size_t)b*SEQ + q0 + w*16 + l15;
  const char* qp = (const char*)Q + (rowQ*E_DIM + h*HEAD_D)*2;
  short8 qf0 = *(const short8*)(qp + l4*16);
  short8 qf1 = *(const short8*)(qp + 64 + l4*16);

  f32x4 zero = {0.f, 0.f, 0.f, 0.f};
  f32x4 oacc[4];
  for (int i = 0; i < 4; ++i) oacc[i] = zero;
  float mrow[4] = {-1e30f, -1e30f, -1e30f, -1e30f};
  float lrow[4] = {0.f, 0.f, 0.f, 0.f};

  const int jr = lane >> 3, jc = lane & 7, kcg = jc ^ jr;
  const int vrow0 = tid >> 3, vdch = tid & 7;

  for (int kt = 0; kt < SEQ/64; ++kt) {
    const int kv0 = kt*64;
    __syncthreads();                         // LDS reuse fence
    // K tile: swizzled global_load_lds (8 issues, 2/wave)
#pragma unroll
    for (int t = 0; t < 2; ++t) {
      int ia = w*2 + t;
      const char* src = (const char*)Kk +
          (((size_t)b*SEQ + kv0 + ia*8 + jr)*E_DIM + h*HEAD_D)*2 + (kcg << 4);
      gload_lds16(src, (char*)K_lds + ia*1024);
    }
    // V tile: reg-staged transpose into Vt_lds[d][kv] (kv-chunk XOR d&7 swizzle)
#pragma unroll
    for (int rep = 0; rep < 2; ++rep) {
      int row = vrow0 + rep*32;
      const char* vsrc = (const char*)V +
          (((size_t)b*SEQ + kv0 + row)*E_DIM + h*HEAD_D + vdch*8)*2;
      short8 vv = *(const short8*)vsrc;
#pragma unroll
      for (int ei = 0; ei < 8; ++ei) {
        int e = (ei + vdch) & 7;             // stagger -> banks spread across dch
        int d = vdch*8 + e;
        int off = d*128 + ((((row >> 3) ^ e) << 4)) + ((row & 7) << 1);
        *(unsigned short*)((char*)Vt_lds + off) = (unsigned short)vv[e];
      }
    }
    __syncthreads();

    // S = Q K^T (already in log2 domain). sf[nf] rows q=l4*4+r, col kv=nf*16+l15
    f32x4 sf[4];
#pragma unroll
    for (int nf = 0; nf < 4; ++nf) {
      const char* kb = (const char*)K_lds + (nf*16 + l15)*128;
      short8 k0 = *(const short8*)(kb + ((l4 ^ l7) << 4));
      short8 k1 = *(const short8*)(kb + (((4 + l4) ^ l7) << 4));
      f32x4 z = zero;
      z = __builtin_amdgcn_mfma_f32_16x16x32_bf16(qf0, k0, z, 0, 0, 0);
      z = __builtin_amdgcn_mfma_f32_16x16x32_bf16(qf1, k1, z, 0, 0, 0);
      sf[nf] = z;
    }
    // online softmax (exp2 domain), rows reduce across the 16 lanes of l4-group
    float fac[4];
#pragma unroll
    for (int r = 0; r < 4; ++r) {
      float v = fmaxf(fmaxf(sf[0][r], sf[1][r]), fmaxf(sf[2][r], sf[3][r]));
#pragma unroll
      for (int off = 1; off < 16; off <<= 1)
        v = fmaxf(v, __shfl_xor(v, off));
      float mn = fmaxf(mrow[r], v);
      fac[r] = exp2f(mrow[r] - mn);
      mrow[r] = mn;
    }
    float rs[4] = {0.f, 0.f, 0.f, 0.f};
#pragma unroll
    for (int nf = 0; nf < 4; ++nf)
#pragma unroll
      for (int r = 0; r < 4; ++r) {
        float p = exp2f(sf[nf][r] - mrow[r]);
        sf[nf][r] = p;
        rs[r] += p;
      }
#pragma unroll
    for (int r = 0; r < 4; ++r) {
#pragma unroll
      for (int off = 1; off < 16; off <<= 1)
        rs[r] += __shfl_xor(rs[r], off);
      lrow[r] = lrow[r]*fac[r] + rs[r];
    }
#pragma unroll
    for (int nf = 0; nf < 4; ++nf) {
      oacc[nf][0] *= fac[0]; oacc[nf][1] *= fac[1];
      oacc[nf][2] *= fac[2]; oacc[nf][3] *= fac[3];
    }
    // P -> bf16 via per-wave LDS (pad 72 -> 2-way max on b128 reads)
    unsigned short* pw = &P_lds[w][0];
#pragma unroll
    for (int nf = 0; nf < 4; ++nf)
#pragma unroll
      for (int r = 0; r < 4; ++r)
        pw[(l4*4 + r)*72 + nf*16 + l15] = f2bf(sf[nf][r]);
    short8 pa0 = *(const short8*)((const char*)pw + l15*144 + l4*16);
    short8 pa1 = *(const short8*)((const char*)pw + l15*144 + 64 + l4*16);
    // O += P V
#pragma unroll
    for (int nf = 0; nf < 4; ++nf) {
      const char* vb = (const char*)Vt_lds + (nf*16 + l15)*128;
      short8 v0 = *(const short8*)(vb + ((l4 ^ l7) << 4));
      short8 v1 = *(const short8*)(vb + (((4 + l4) ^ l7) << 4));
      oacc[nf] = __builtin_amdgcn_mfma_f32_16x16x32_bf16(pa0, v0, oacc[nf], 0, 0, 0);
      oacc[nf] = __builtin_amdgcn_mfma_f32_16x16x32_bf16(pa1, v1, oacc[nf], 0, 0, 0);
    }
  }
  // normalize + store O (bf16, [b,s,h*d] packed)
  const size_t obase = ((size_t)b*SEQ + q0 + w*16)*E_DIM + h*HEAD_D;
#pragma unroll
  for (int nf = 0; nf < 4; ++nf) {
    const int col = nf*16 + l15;
#pragma unroll
    for (int r = 0; r < 4; ++r) {
      float v = oacc[nf][r] / lrow[r];
      O[obase + (size_t)(l4*4 + r)*E_DIM + col] = f2bf(v);
    }
  }
}

extern "C" void kernel_launch(void* const* d_in, const int* in_sizes, int n_in,
                              void* d_out, int out_size, void* d_ws, size_t ws_size,
                              hipStream_t stream) {
  const float* q_in = (const float*)d_in[0];
  const float* k_in = (const float*)d_in[1];
  const float* v_in = (const float*)d_in[2];
  const float* Wq = (const float*)d_in[3];
  const float* bq = (const float*)d_in[4];
  const float* Wk = (const float*)d_in[5];
  const float* bk = (const float*)d_in[6];
  const float* Wv = (const float*)d_in[7];
  const float* bv = (const float*)d_in[8];
  const float* Wo = (const float*)d_in[9];
  const float* bo = (const float*)d_in[10];

  char* ws = (char*)d_ws;
  const size_t XB = (size_t)M_ROWS * E_DIM * 2;   // 8 MiB
  const size_t WB = (size_t)E_DIM * E_DIM * 2;    // 2 MiB
  unsigned short* Xq  = (unsigned short*)(ws);
  unsigned short* Xk  = (unsigned short*)(ws + XB);
  unsigned short* Xv  = (unsigned short*)(ws + 2*XB);
  unsigned short* Wqb = (unsigned short*)(ws + 3*XB);
  unsigned short* Wkb = (unsigned short*)(ws + 3*XB + WB);
  unsigned short* Wvb = (unsigned short*)(ws + 3*XB + 2*WB);
  unsigned short* Wob = (unsigned short*)(ws + 3*XB + 3*WB);
  unsigned short* Qb  = (unsigned short*)(ws + 3*XB + 4*WB);
  unsigned short* Kb  = (unsigned short*)(ws + 4*XB + 4*WB);
  unsigned short* Vb  = (unsigned short*)(ws + 5*XB + 4*WB);
  unsigned short* Ob  = (unsigned short*)(ws + 6*XB + 4*WB);  // ends at 64 MiB

  const int nX8 = M_ROWS * E_DIM / 8;   // 524288
  const int nW8 = E_DIM * E_DIM / 8;    // 131072
  cvt_f32_bf16<<<nX8/256, 256, 0, stream>>>(q_in, Xq, nX8);
  cvt_f32_bf16<<<nX8/256, 256, 0, stream>>>(k_in, Xk, nX8);
  cvt_f32_bf16<<<nX8/256, 256, 0, stream>>>(v_in, Xv, nX8);
  cvt_f32_bf16<<<nW8/256, 256, 0, stream>>>(Wq, Wqb, nW8);
  cvt_f32_bf16<<<nW8/256, 256, 0, stream>>>(Wk, Wkb, nW8);
  cvt_f32_bf16<<<nW8/256, 256, 0, stream>>>(Wv, Wvb, nW8);
  cvt_f32_bf16<<<nW8/256, 256, 0, stream>>>(Wo, Wob, nW8);

  dim3 ggrid(E_DIM/64, M_ROWS/128);     // 16 x 32 = 512 blocks
  const float qscale = 0.125f * 1.44269504088896340736f;  // scale * log2(e)
  gemm_bt<1><<<ggrid, 256, 0, stream>>>(Xq, Wqb, bq, Qb, M_ROWS, E_DIM, E_DIM, qscale);
  gemm_bt<1><<<ggrid, 256, 0, stream>>>(Xk, Wkb, bk, Kb, M_ROWS, E_DIM, E_DIM, 1.0f);
  gemm_bt<1><<<ggrid, 256, 0, stream>>>(Xv, Wvb, bv, Vb, M_ROWS, E_DIM, E_DIM, 1.0f);

  dim3 agrid(SEQ/64, BATCH*N_HEADS);    // 32 x 32 = 1024 blocks
  attn_fwd<<<agrid, 256, 0, stream>>>(Qb, Kb, Vb, Ob);

  gemm_bt<0><<<ggrid, 256, 0, stream>>>(Ob, Wob, bo, d_out, M_ROWS, E_DIM, E_DIM, 1.0f);
}

// Round 5
// 168.081 us; speedup vs baseline: 1.4765x; 1.4765x over previous
//
#include <hip/hip_runtime.h>
#include <stdint.h>

#define E_DIM 1024
#define N_HEADS 16
#define HEAD_D 64
#define BATCH 2
#define SEQ 2048
#define M_ROWS (BATCH*SEQ)   // 4096

typedef __attribute__((ext_vector_type(8))) short short8;
typedef __attribute__((ext_vector_type(4))) short short4_t;
typedef __attribute__((ext_vector_type(4))) float f32x4;
typedef __attribute__((ext_vector_type(4))) int i32x4;
typedef __attribute__((ext_vector_type(2))) int i32x2;

__device__ __forceinline__ unsigned short f2bf(float f) {
  uint32_t u = __float_as_uint(f);
  u += 0x7FFFu + ((u >> 16) & 1u);   // RTNE
  return (unsigned short)(u >> 16);
}

// async global->LDS, 16B per lane; LDS dest = wave-uniform base + lane*16
__device__ __forceinline__ void gload_lds16(const void* g, void* l) {
  __builtin_amdgcn_global_load_lds(
      (const __attribute__((address_space(1))) uint32_t*)(uintptr_t)g,
      (__attribute__((address_space(3))) uint32_t*)(uint32_t)(uintptr_t)l,
      16, 0, 0);
}

__device__ __forceinline__ int cvtpk(float lo, float hi) {
  int r;
  asm("v_cvt_pk_bf16_f32 %0, %1, %2" : "=v"(r) : "v"(lo), "v"(hi));
  return r;
}

__global__ void cvt_f32_bf16(const float* __restrict__ src,
                             unsigned short* __restrict__ dst, int n8) {
  int i = blockIdx.x * blockDim.x + threadIdx.x;
  if (i >= n8) return;
  f32x4 a = ((const f32x4*)src)[2*i];
  f32x4 b = ((const f32x4*)src)[2*i + 1];
  union { unsigned short us[8]; i32x4 v; } o;
  o.us[0] = f2bf(a[0]); o.us[1] = f2bf(a[1]);
  o.us[2] = f2bf(a[2]); o.us[3] = f2bf(a[3]);
  o.us[4] = f2bf(b[0]); o.us[5] = f2bf(b[1]);
  o.us[6] = f2bf(b[2]); o.us[7] = f2bf(b[3]);
  ((i32x4*)dst)[i] = o.v;
}

// C[m][n] = (sum_k A[m][k]*B[n][k] + bias[n]) * scale   (verified in R1)
template<int OUT_BF16>
__global__ __launch_bounds__(256, 2)
void gemm_bt(const unsigned short* __restrict__ A,
             const unsigned short* __restrict__ Bm,
             const float* __restrict__ bias,
             void* __restrict__ Cout,
             int M, int N, int K, float scale) {
  constexpr int BM = 128, BN = 64, BK = 64;
  __shared__ __attribute__((aligned(16))) unsigned short Al[BM*BK];
  __shared__ __attribute__((aligned(16))) unsigned short Bl[BN*BK];
  const int tid  = threadIdx.x;
  const int lane = tid & 63, w = tid >> 6;
  const int wm = w >> 1, wn = w & 1;
  const int l15 = lane & 15, l4 = lane >> 4, l7 = lane & 7;
  const int m0 = blockIdx.y * BM, n0 = blockIdx.x * BN;
  const int jr = lane >> 3, jc = lane & 7;
  const int kcg = jc ^ jr;

  f32x4 zero = {0.f, 0.f, 0.f, 0.f};
  f32x4 acc[4][2];
  for (int i = 0; i < 4; ++i) for (int j = 0; j < 2; ++j) acc[i][j] = zero;

  for (int kt = 0; kt < K; kt += BK) {
    __syncthreads();
#pragma unroll
    for (int t = 0; t < 4; ++t) {
      int ia = w*4 + t;
      const char* src = (const char*)A +
          ((size_t)(m0 + ia*8 + jr)*K + kt)*2 + (kcg << 4);
      gload_lds16(src, (char*)Al + ia*1024);
    }
#pragma unroll
    for (int t = 0; t < 2; ++t) {
      int ib = w*2 + t;
      const char* src = (const char*)Bm +
          ((size_t)(n0 + ib*8 + jr)*K + kt)*2 + (kcg << 4);
      gload_lds16(src, (char*)Bl + ib*1024);
    }
    __syncthreads();
#pragma unroll
    for (int ks = 0; ks < 2; ++ks) {
      const int sw = ((ks*4 + l4) ^ l7) << 4;
      short8 af[4], bf[2];
#pragma unroll
      for (int mf = 0; mf < 4; ++mf)
        af[mf] = *(const short8*)((const char*)Al + (wm*64 + mf*16 + l15)*128 + sw);
#pragma unroll
      for (int nf = 0; nf < 2; ++nf)
        bf[nf] = *(const short8*)((const char*)Bl + (wn*32 + nf*16 + l15)*128 + sw);
#pragma unroll
      for (int mf = 0; mf < 4; ++mf)
#pragma unroll
        for (int nf = 0; nf < 2; ++nf)
          acc[mf][nf] = __builtin_amdgcn_mfma_f32_16x16x32_bf16(
              af[mf], bf[nf], acc[mf][nf], 0, 0, 0);
    }
  }
#pragma unroll
  for (int nf = 0; nf < 2; ++nf) {
    const int col = n0 + wn*32 + nf*16 + l15;
    const float bv = bias[col];
#pragma unroll
    for (int mf = 0; mf < 4; ++mf) {
      const int rowb = m0 + wm*64 + mf*16 + l4*4;
#pragma unroll
      for (int r = 0; r < 4; ++r) {
        float v = (acc[mf][nf][r] + bv) * scale;
        if (OUT_BF16)
          ((unsigned short*)Cout)[(size_t)(rowb + r)*N + col] = f2bf(v);
        else
          ((float*)Cout)[(size_t)(rowb + r)*N + col] = v;
      }
    }
  }
}

// ---------------------------------------------------------------------------
// Flash attention — ONLY R1-verified mechanisms (16x16x32 MFMA, XOR-swizzle
// store/read pairs, gload_lds linear staging, scatter transpose, shfl_xor).
// 8 waves x 16 q-rows = 128-q tile. KV tiles of 64, double-buffered.
//   S^T[kv][q] = mfma(K-frag, Q-frag)  -> lane owns 16 kv of ONE q (q=l15)
//   softmax: 15 in-reg fmax + shfl_xor(16,32); per-lane scalar m,l,fac
//   P^T packed to per-wave LDS as 4x ds_write_b64 (chunk-XOR swizzled)
//   O^T[d][q] = mfma(Vt-frag, P-frag)  -> rescale by scalar fac
// Q pre-scaled by 0.125*log2(e) -> exp2 domain.
// Kl/Vt: row-major [64 rows][64 cols], 16B chunks XOR-swizzled by (row&7).
// ---------------------------------------------------------------------------
__global__ __launch_bounds__(512, 2)
void attn_fwd3(const unsigned short* __restrict__ Q,
               const unsigned short* __restrict__ Kg,
               const unsigned short* __restrict__ Vg,
               unsigned short* __restrict__ O) {
  __shared__ __attribute__((aligned(16))) unsigned short Kl[2][4096];
  __shared__ __attribute__((aligned(16))) unsigned short Vt[2][4096];
  __shared__ __attribute__((aligned(16))) unsigned short Pl[8][1024];

  const int tid = threadIdx.x;
  const int l = tid & 63, w = tid >> 6;
  const int l15 = l & 15, l4 = l >> 4, l7 = l & 7;

  // XCD-aware bijective decode: 512 blocks = 16 qt x 32 bh; XCD x gets bh 4x..4x+3
  const int id = blockIdx.x;
  const int bh = (id & 7) * 4 + ((id >> 3) & 3);
  const int qt = id >> 5;
  const int b = bh >> 4, h = bh & 15;
  const size_t bS = (size_t)b * SEQ;
  const int qw = qt * 128 + w * 16;             // wave's q base

  // Q fragments (held in regs): lane holds Q[q=qw+l15][e = ks*32 + l4*8 + j]
  short8 qf[2];
  {
    const char* qp = (const char*)Q + ((bS + qw + l15) * E_DIM + h * 64) * 2;
    qf[0] = *(const short8*)(qp + l4 * 16);
    qf[1] = *(const short8*)(qp + 64 + l4 * 16);
  }

  f32x4 zero = {0.f, 0.f, 0.f, 0.f};
  f32x4 oacc[4];                                 // O^T: d=df*16+l4*4+r, q=l15
#pragma unroll
  for (int i = 0; i < 4; ++i) oacc[i] = zero;
  float mrow = -1e30f, lrow = 0.f;

  // staging maps
  const int krow = l >> 3;                       // 0..7
  const int kcg  = (l & 7) ^ krow;               // inverse-swizzled source octet
  const int vd0  = (l & 7) * 8;                  // d block this thread loads

#define KSTAGE(KT, BUF)                                                        \
  gload_lds16((const char*)Kg +                                                \
                  ((bS + (size_t)(KT)*64 + 8*w + krow) * E_DIM + h*64 + kcg*8)*2, \
              (char*)Kl[BUF] + w * 1024)

#define VLOAD(KT)                                                              \
  (*(const short8*)((const char*)Vg +                                          \
      ((bS + (size_t)(KT)*64 + 8*w + krow) * E_DIM + h*64 + vd0) * 2))

  // scatter Vt[buf][d][kv]: byte = d*128 + ((w^ (d&7))<<4) + ((kv&7)<<1); kv = 8w+krow
#define VSCATTER(VV, BUF)                                                      \
  do {                                                                         \
    char* vbase_ = (char*)Vt[BUF] + (krow << 1);                               \
    _Pragma("unroll")                                                          \
    for (int ei = 0; ei < 8; ++ei) {                                           \
      int e_ = (ei + (l & 7)) & 7;                                             \
      int d_ = vd0 + e_;                                                       \
      *(unsigned short*)(vbase_ + d_ * 128 + ((w ^ e_) << 4)) =                \
          (unsigned short)(VV)[e_];                                            \
    }                                                                          \
  } while (0)

  // prologue: tile 0
  {
    short8 v0r = VLOAD(0);
    KSTAGE(0, 0);
    VSCATTER(v0r, 0);
  }
  __syncthreads();

  int cur = 0;
  constexpr int NT = SEQ / 64;
  for (int kt = 0; kt < NT; ++kt) {
    short8 vnext;
    const bool more = (kt + 1 < NT);
    if (more) {
      KSTAGE(kt + 1, cur ^ 1);
      vnext = VLOAD(kt + 1);
    }

    // ---- S^T = K Q^T : lane -> S[kv = nf*16 + l4*4 + r][q = qw + l15] ----
    f32x4 s[4];
    const char* kb = (const char*)Kl[cur];
#pragma unroll
    for (int nf = 0; nf < 4; ++nf) {
      const char* rowb = kb + (nf * 16 + l15) * 128;
      short8 k0 = *(const short8*)(rowb + ((l4 ^ l7) << 4));
      short8 k1 = *(const short8*)(rowb + (((4 + l4) ^ l7) << 4));
      f32x4 z = zero;
      z = __builtin_amdgcn_mfma_f32_16x16x32_bf16(k0, qf[0], z, 0, 0, 0);
      z = __builtin_amdgcn_mfma_f32_16x16x32_bf16(k1, qf[1], z, 0, 0, 0);
      s[nf] = z;
    }

    // ---- online softmax: per-lane scalar (q = l15; l4-groups hold kv quarters)
    float mx = s[0][0];
#pragma unroll
    for (int nf = 0; nf < 4; ++nf)
#pragma unroll
      for (int r = 0; r < 4; ++r) mx = fmaxf(mx, s[nf][r]);
    mx = fmaxf(mx, __shfl_xor(mx, 16));
    mx = fmaxf(mx, __shfl_xor(mx, 32));
    const float mnew = fmaxf(mrow, mx);
    const float fac = __builtin_amdgcn_exp2f(mrow - mnew);
    mrow = mnew;

    float pv[4][4];
    float rs = 0.f;
#pragma unroll
    for (int nf = 0; nf < 4; ++nf)
#pragma unroll
      for (int r = 0; r < 4; ++r) {
        float p = __builtin_amdgcn_exp2f(s[nf][r] - mnew);
        pv[nf][r] = p;
        rs += p;
      }
    rs += __shfl_xor(rs, 16);
    rs += __shfl_xor(rs, 32);
    lrow = lrow * fac + rs;

    // ---- P -> per-wave LDS, packed b64, chunk-XOR swizzle by q(&7)=l7 ----
    unsigned short* pw = Pl[w];
#pragma unroll
    for (int nf = 0; nf < 4; ++nf) {
      const int c = nf * 2 + (l4 >> 1);
      i32x2 pk;
      pk.x = cvtpk(pv[nf][0], pv[nf][1]);
      pk.y = cvtpk(pv[nf][2], pv[nf][3]);
      *(i32x2*)((char*)pw + l15 * 128 + ((c ^ l7) << 4) + ((l4 & 1) << 3)) = pk;
    }
    // B-fragments: P[q=l15][kv = ks*32 + l4*8 + j]
    short8 pf0 = *(const short8*)((const char*)pw + l15 * 128 + ((l4 ^ l7) << 4));
    short8 pf1 = *(const short8*)((const char*)pw + l15 * 128 + (((4 + l4) ^ l7) << 4));

    // ---- rescale + O^T += V^T P^T ----
#pragma unroll
    for (int df = 0; df < 4; ++df)
#pragma unroll
      for (int r = 0; r < 4; ++r) oacc[df][r] *= fac;

    const char* vb = (const char*)Vt[cur];
#pragma unroll
    for (int df = 0; df < 4; ++df) {
      const char* rowb = vb + (df * 16 + l15) * 128;
      short8 v0 = *(const short8*)(rowb + ((l4 ^ l7) << 4));
      short8 v1 = *(const short8*)(rowb + (((4 + l4) ^ l7) << 4));
      oacc[df] = __builtin_amdgcn_mfma_f32_16x16x32_bf16(v0, pf0, oacc[df], 0, 0, 0);
      oacc[df] = __builtin_amdgcn_mfma_f32_16x16x32_bf16(v1, pf1, oacc[df], 0, 0, 0);
    }

    if (more) VSCATTER(vnext, cur ^ 1);
    __syncthreads();   // drains vmcnt+lgkmcnt: next buffers staged, cur free
    cur ^= 1;
  }
#undef KSTAGE
#undef VLOAD
#undef VSCATTER

  // ---- epilogue: O[q = qw+l15][d = df*16 + l4*4 + r] ----
  const float rinv = __builtin_amdgcn_rcpf(lrow);
  unsigned short* orow = O + (bS + qw + l15) * E_DIM + h * 64;
#pragma unroll
  for (int df = 0; df < 4; ++df) {
    short4_t o4;
#pragma unroll
    for (int r = 0; r < 4; ++r) o4[r] = (short)f2bf(oacc[df][r] * rinv);
    *(short4_t*)(orow + df * 16 + l4 * 4) = o4;
  }
}

extern "C" void kernel_launch(void* const* d_in, const int* in_sizes, int n_in,
                              void* d_out, int out_size, void* d_ws, size_t ws_size,
                              hipStream_t stream) {
  const float* q_in = (const float*)d_in[0];
  const float* k_in = (const float*)d_in[1];
  const float* v_in = (const float*)d_in[2];
  const float* Wq = (const float*)d_in[3];
  const float* bq = (const float*)d_in[4];
  const float* Wk = (const float*)d_in[5];
  const float* bk = (const float*)d_in[6];
  const float* Wv = (const float*)d_in[7];
  const float* bv = (const float*)d_in[8];
  const float* Wo = (const float*)d_in[9];
  const float* bo = (const float*)d_in[10];

  char* ws = (char*)d_ws;
  const size_t XB = (size_t)M_ROWS * E_DIM * 2;   // 8 MiB
  const size_t WB = (size_t)E_DIM * E_DIM * 2;    // 2 MiB
  unsigned short* Xq  = (unsigned short*)(ws);
  unsigned short* Xk  = (unsigned short*)(ws + XB);
  unsigned short* Xv  = (unsigned short*)(ws + 2*XB);
  unsigned short* Wqb = (unsigned short*)(ws + 3*XB);
  unsigned short* Wkb = (unsigned short*)(ws + 3*XB + WB);
  unsigned short* Wvb = (unsigned short*)(ws + 3*XB + 2*WB);
  unsigned short* Wob = (unsigned short*)(ws + 3*XB + 3*WB);
  unsigned short* Qb  = (unsigned short*)(ws + 3*XB + 4*WB);
  unsigned short* Kb  = (unsigned short*)(ws + 4*XB + 4*WB);
  unsigned short* Vb  = (unsigned short*)(ws + 5*XB + 4*WB);
  unsigned short* Ob  = (unsigned short*)(ws + 6*XB + 4*WB);  // ends at 64 MiB

  const int nX8 = M_ROWS * E_DIM / 8;   // 524288
  const int nW8 = E_DIM * E_DIM / 8;    // 131072
  cvt_f32_bf16<<<nX8/256, 256, 0, stream>>>(q_in, Xq, nX8);
  cvt_f32_bf16<<<nX8/256, 256, 0, stream>>>(k_in, Xk, nX8);
  cvt_f32_bf16<<<nX8/256, 256, 0, stream>>>(v_in, Xv, nX8);
  cvt_f32_bf16<<<nW8/256, 256, 0, stream>>>(Wq, Wqb, nW8);
  cvt_f32_bf16<<<nW8/256, 256, 0, stream>>>(Wk, Wkb, nW8);
  cvt_f32_bf16<<<nW8/256, 256, 0, stream>>>(Wv, Wvb, nW8);
  cvt_f32_bf16<<<nW8/256, 256, 0, stream>>>(Wo, Wob, nW8);

  dim3 ggrid(E_DIM/64, M_ROWS/128);     // 16 x 32 = 512 blocks
  const float qscale = 0.125f * 1.44269504088896340736f;  // scale * log2(e)
  gemm_bt<1><<<ggrid, 256, 0, stream>>>(Xq, Wqb, bq, Qb, M_ROWS, E_DIM, E_DIM, qscale);
  gemm_bt<1><<<ggrid, 256, 0, stream>>>(Xk, Wkb, bk, Kb, M_ROWS, E_DIM, E_DIM, 1.0f);
  gemm_bt<1><<<ggrid, 256, 0, stream>>>(Xv, Wvb, bv, Vb, M_ROWS, E_DIM, E_DIM, 1.0f);

  attn_fwd3<<<512, 512, 0, stream>>>(Qb, Kb, Vb, Ob);   // 16 qt x 32 bh, xcd-swizzled

  gemm_bt<0><<<ggrid, 256, 0, stream>>>(Ob, Wob, bo, d_out, M_ROWS, E_DIM, E_DIM, 1.0f);
}